// Round 5
// baseline (95.807 us; speedup 1.0000x reference)
//
#include <hip/hip_runtime.h>
#include <cstdint>

typedef __bf16 bf16x8 __attribute__((ext_vector_type(8)));
typedef float floatx4 __attribute__((ext_vector_type(4)));

// M = 4096 rows, C(K) = 256. Phase-isolated pipeline (round-5 experiment:
// every dispatch individually roofline-predictable, to localize the ~40 us
// mystery stall that survived rounds 0-4 in the fused gemm+epilogue):
//   K0 transpose_stage: fp32 -> staged bf16 (12 MB traffic, ~2.5 us)
//   K1 gemm_c: 256x256 tiles, R4 skeleton (global_load_lds, counted vmcnt,
//      XCD swizzle) but epilogue = plain C stores (64 MB f32 lossmat)
//   K2 combine: row-linear full softmax from lossmat (coalesced, row in
//      VGPRs, one 6-step wave reduce per row; no shfl chains per element)
//   K3 finalize: reduce 128 block partials. No device-scope fences at all.
//
// Staged layout: Xs[rb(32)][s(4)][kk(2)][rowhi(8)][quad(4)][rowlo(16)][8 bf16]
// holding X[row = rb*128+rowhi*16+rowlo][k = s*64+kk*32+quad*8+j]; lane-linear
// for global_load_lds AND conflict-free (2-way) for ds_read_b128 fragments.

#define OFF_X     (0u)
#define OFF_Y     (2u*1024*1024)
#define OFF_LPART (4u*1024*1024)
#define OFF_CPART (4u*1024*1024 + 4096u)
#define OFF_LM    (16u*1024*1024)          // 4096x4096 f32 = 64 MB

#define AS1C(p) ((const __attribute__((address_space(1))) void*)(const void*)(p))
#define AS3(p)  ((__attribute__((address_space(3))) void*)(void*)(p))

// ---------------------------------------------------------------------------
// K0: fp32 -> staged bf16. One block per (b,n) slab (16 rows x 256 c = 16 KB
// contiguous input).
// ---------------------------------------------------------------------------
__global__ __launch_bounds__(256) void transpose_stage(
    const float* __restrict__ pred, const float* __restrict__ gt,
    unsigned short* __restrict__ Xs, unsigned short* __restrict__ Ys) {
  int blk = blockIdx.x;
  const int t = threadIdx.x;
  const float* src;
  unsigned short* dst;
  int slab;
  if (blk < 256) { src = pred; dst = Xs; slab = blk; }
  else           { src = gt;   dst = Ys; slab = blk - 256; }
  const float* sb = src + slab * 4096;
  const int rb = slab >> 3, rowhi = slab & 7;
  #pragma unroll
  for (int half = 0; half < 2; ++half) {
    int c_ = half * 256 + t;                 // chunk id within slab, 0..511
    int rowlo = c_ & 15;
    int quad  = (c_ >> 4) & 3;
    int kk    = (c_ >> 6) & 1;
    int s     = c_ >> 7;
    int k0 = s * 64 + kk * 32 + quad * 8;
    unsigned int packed[4];
    #pragma unroll
    for (int jj = 0; jj < 4; ++jj) {
      unsigned int lohi[2];
      #pragma unroll
      for (int e = 0; e < 2; ++e) {
        float f = sb[(k0 + jj * 2 + e) * 16 + rowlo];
        unsigned int u = __float_as_uint(f);
        lohi[e] = (u + 0x7FFFu + ((u >> 16) & 1u)) >> 16;   // RNE -> bf16
      }
      packed[jj] = lohi[0] | (lohi[1] << 16);
    }
    unsigned short* o = dst + rb * 32768 +
        (unsigned)(s * 1024 + kk * 512 + rowhi * 64 + quad * 16 + rowlo) * 8;
    uint4 v; v.x = packed[0]; v.y = packed[1]; v.z = packed[2]; v.w = packed[3];
    *reinterpret_cast<uint4*>(o) = v;
  }
}

// ---------------------------------------------------------------------------
// K1: lossmat tile (256x256) = X @ Y^T -> LM (f32). R4 skeleton: 512 threads,
// 8 waves 2x4, wave tile 128x64 = 8x4 frags; K in 4 slabs of 64 via dbuf
// 128 KB LDS; counted vmcnt(8) + raw s_barrier; XCD-chunked block mapping.
// Epilogue: plain global stores of the tile (predictable, fire-and-forget).
// ---------------------------------------------------------------------------
__global__ __launch_bounds__(512) void gemm_c(
    const unsigned short* __restrict__ Xs, const unsigned short* __restrict__ Ys,
    float* __restrict__ LM) {
  __shared__ __align__(16) unsigned short As[2][16384];  // 2 x 32 KB
  __shared__ __align__(16) unsigned short Bs[2][16384];  // 2 x 32 KB
  const int t = threadIdx.x;
  const int wave = t >> 6, lane = t & 63;
  const int rg = wave >> 2, cg = wave & 3;
  const int h = blockIdx.x;
  const int xcd = h & 7, slot = h >> 3;
  const int bR = ((xcd >> 1) << 2) | (slot & 3);
  const int bC = ((xcd & 1) << 3) | (slot >> 2);
  const unsigned short* Ag = Xs + bR * 65536;   // rb groups 2bR, 2bR+1
  const unsigned short* Bg = Ys + bC * 65536;

  floatx4 acc[8][4];
  const floatx4 zero = {0.f, 0.f, 0.f, 0.f};
  #pragma unroll
  for (int i = 0; i < 8; ++i)
    #pragma unroll
    for (int j = 0; j < 4; ++j) acc[i][j] = zero;

#define STAGE(BUF, S) do {                                                   \
    _Pragma("unroll") for (int it = 0; it < 4; ++it) {                       \
      int chunk = it * 512 + t;              /* 0..2047 */                   \
      int half = chunk >> 10, w_ = chunk & 1023;                             \
      __builtin_amdgcn_global_load_lds(                                      \
          AS1C(Ag + half * 32768 + (S) * 8192 + w_ * 8),                     \
          AS3(&As[BUF][(unsigned)chunk * 8]), 16, 0, 0);                     \
      __builtin_amdgcn_global_load_lds(                                      \
          AS1C(Bg + half * 32768 + (S) * 8192 + w_ * 8),                     \
          AS3(&Bs[BUF][(unsigned)chunk * 8]), 16, 0, 0);                     \
    }                                                                        \
  } while (0)

#define COMPUTE(BUF) do {                                                    \
    _Pragma("unroll") for (int kk = 0; kk < 2; ++kk) {                       \
      bf16x8 b[4];                                                           \
      _Pragma("unroll") for (int fc = 0; fc < 4; ++fc) {                     \
        int gc = cg * 4 + fc;                                                \
        b[fc] = *reinterpret_cast<const bf16x8*>(                            \
            &Bs[BUF][(unsigned)((gc >> 3) * 8192 + kk * 4096 +               \
                                (gc & 7) * 512 + lane * 8)]);                \
      }                                                                      \
      _Pragma("unroll") for (int fr = 0; fr < 8; ++fr) {                     \
        bf16x8 a = *reinterpret_cast<const bf16x8*>(                         \
            &As[BUF][(unsigned)(rg * 8192 + kk * 4096 + fr * 512 +           \
                                lane * 8)]);                                 \
        _Pragma("unroll") for (int fc = 0; fc < 4; ++fc)                     \
          acc[fr][fc] = __builtin_amdgcn_mfma_f32_16x16x32_bf16(             \
              a, b[fc], acc[fr][fc], 0, 0, 0);                               \
      }                                                                      \
    }                                                                        \
  } while (0)

#define BAR_ACQ(N) do {                                                      \
    asm volatile("s_waitcnt vmcnt(" #N ")" ::: "memory");                    \
    __builtin_amdgcn_s_barrier();                                            \
    asm volatile("" ::: "memory");                                           \
  } while (0)
#define BAR_REL() do {                                                       \
    asm volatile("" ::: "memory");                                           \
    __builtin_amdgcn_s_barrier();                                            \
  } while (0)

  STAGE(0, 0);
  STAGE(1, 1);
  BAR_ACQ(8);          // slab 0 resident; slab 1's 8 loads still in flight
  COMPUTE(0);
  BAR_REL();           // all waves done with buf0
  STAGE(0, 2);
  BAR_ACQ(8);          // slab 1 resident; slab 2 in flight
  COMPUTE(1);
  BAR_REL();
  STAGE(1, 3);
  BAR_ACQ(8);          // slab 2 resident; slab 3 in flight
  COMPUTE(0);
  BAR_ACQ(0);          // slab 3 resident
  COMPUTE(1);

#undef STAGE
#undef COMPUTE
#undef BAR_ACQ
#undef BAR_REL

  const int quad = lane >> 4, lc = lane & 15;
  // C store: row_local = rg*128 + fr*16 + quad*4 + r,
  //          col_local = cg*64 + fc*16 + lc.
  float* Cb = LM + (size_t)(bR * 256 + rg * 128 + quad * 4) * 4096 +
              bC * 256 + cg * 64 + lc;
  #pragma unroll
  for (int fr = 0; fr < 8; ++fr)
    #pragma unroll
    for (int r = 0; r < 4; ++r)
      #pragma unroll
      for (int fc = 0; fc < 4; ++fc)
        Cb[(size_t)(fr * 16 + r) * 4096 + fc * 16] = acc[fr][fc][r];
}

// ---------------------------------------------------------------------------
// K2: full softmax per row from LM. 128 blocks x 256 thr; 4 waves/block;
// each wave owns 8 consecutive rows. Row (4096 f32 = 16 KB) is read with 16
// coalesced float4 loads into registers, reduced serially in-lane, then one
// 6-step wave reduce for max and one for sum. diag = LM[row][row].
// ---------------------------------------------------------------------------
__global__ __launch_bounds__(256) void combine_full(
    const float* __restrict__ LM,
    float* __restrict__ lpart, float* __restrict__ cpart) {
  const int t = threadIdx.x;
  const int wave = t >> 6, lane = t & 63;
  const int w_global = blockIdx.x * 4 + wave;
  float lossacc = 0.f, corracc = 0.f;
  #pragma unroll 1
  for (int rr = 0; rr < 8; ++rr) {
    int row = w_global * 8 + rr;
    const float4* rp = reinterpret_cast<const float4*>(LM + (size_t)row * 4096);
    float4 f[16];
    #pragma unroll
    for (int it = 0; it < 16; ++it) f[it] = rp[it * 64 + lane];
    float m = -3.4e38f;
    #pragma unroll
    for (int it = 0; it < 16; ++it)
      m = fmaxf(m, fmaxf(fmaxf(f[it].x, f[it].y), fmaxf(f[it].z, f[it].w)));
    #pragma unroll
    for (int sh = 1; sh < 64; sh <<= 1) m = fmaxf(m, __shfl_xor(m, sh, 64));
    float ss = 0.f;
    #pragma unroll
    for (int it = 0; it < 16; ++it)
      ss += __expf(f[it].x - m) + __expf(f[it].y - m) +
            __expf(f[it].z - m) + __expf(f[it].w - m);
    #pragma unroll
    for (int sh = 1; sh < 64; sh <<= 1) ss += __shfl_xor(ss, sh, 64);
    float d = LM[(size_t)row * 4096 + row];     // broadcast read
    lossacc += logf(ss) + m - d;
    corracc += (d == m) ? 1.f : 0.f;
  }
  __shared__ float ls[4], cs[4];
  if (lane == 0) { ls[wave] = lossacc; cs[wave] = corracc; }
  __syncthreads();
  if (t == 0) {
    lpart[blockIdx.x] = ls[0] + ls[1] + ls[2] + ls[3];
    cpart[blockIdx.x] = cs[0] + cs[1] + cs[2] + cs[3];
  }
}

// ---------------------------------------------------------------------------
// K3: reduce 128 block partials -> out. One wave.
// ---------------------------------------------------------------------------
__global__ void finalize(const float* __restrict__ lpart,
                         const float* __restrict__ cpart,
                         float* __restrict__ out) {
  int t = threadIdx.x;
  float l = lpart[t] + lpart[t + 64];
  float c = cpart[t] + cpart[t + 64];
  #pragma unroll
  for (int sh = 1; sh < 64; sh <<= 1) {
    l += __shfl_xor(l, sh, 64);
    c += __shfl_xor(c, sh, 64);
  }
  if (t == 0) {
    out[0] = l * (1.f / 4096.f);
    out[1] = c * (100.f / 4096.f);
  }
}

extern "C" void kernel_launch(void* const* d_in, const int* in_sizes, int n_in,
                              void* d_out, int out_size, void* d_ws, size_t ws_size,
                              hipStream_t stream) {
  const float* pred = (const float*)d_in[0];
  const float* gt   = (const float*)d_in[1];
  char* w = (char*)d_ws;
  unsigned short* Xbf = (unsigned short*)(w + OFF_X);
  unsigned short* Ybf = (unsigned short*)(w + OFF_Y);
  float* lpart = (float*)(w + OFF_LPART);
  float* cpart = (float*)(w + OFF_CPART);
  float* LM    = (float*)(w + OFF_LM);
  float* out   = (float*)d_out;

  transpose_stage<<<512, 256, 0, stream>>>(pred, gt, Xbf, Ybf);
  gemm_c<<<256, 512, 0, stream>>>(Xbf, Ybf, LM);
  combine_full<<<128, 256, 0, stream>>>(LM, lpart, cpart);
  finalize<<<1, 64, 0, stream>>>(lpart, cpart, out);
}

// Round 6
// 91.404 us; speedup vs baseline: 1.0482x; 1.0482x over previous
//
#include <hip/hip_runtime.h>
#include <cstdint>

typedef __bf16 bf16x8 __attribute__((ext_vector_type(8)));
typedef float floatx4 __attribute__((ext_vector_type(4)));

// M = 4096 rows, C(K) = 256. Round-6 theory: all prior GEMM variants ran at
// <=2 waves/SIMD in barrier lockstep -> every L2/LDS latency fully exposed
// (~40 us at MfmaUtil 6%). This round: barrier-free, LDS-free GEMM with
// 16 waves/CU. Each wave computes a 64x64 tile, loading MFMA fragments
// DIRECTLY from the staged global layout (it is fragment-linear: 16 B/lane
// coalesced), 8 K-steps of {8 global loads -> 16 MFMA}, fully unrolled.
//
// Staged layout: Xs[rb(32)][s(4)][kk(2)][rowhi(8)][quad(4)][rowlo(16)][8 bf16]
// holding X[row = rb*128+rowhi*16+rowlo][k = s*64+kk*32+quad*8+j].
// Fragment for 16-row group rowhi at K-step (s,kk): lane reads 16 B at
//   Xs + rb*32768 + (s*1024 + kk*512 + rowhi*64 + lane)*8.

#define OFF_X     (0u)
#define OFF_Y     (2u*1024*1024)
#define OFF_PMAX  (4u*1024*1024)
#define OFF_PSUM  (5u*1024*1024)
#define OFF_DIAG  (6u*1024*1024)
#define OFF_LPART (OFF_DIAG + 16384u)
#define OFF_CPART (OFF_LPART + 256u)
#define OFF_CNT   (OFF_CPART + 256u)   // cnt[0]: combine arrival counter

// ---------------------------------------------------------------------------
// K0: fp32 -> staged bf16. One block per (b,n) slab (16 rows x 256 c = 16 KB
// contiguous input). Block 0 zeroes the combine counter.
// ---------------------------------------------------------------------------
__global__ __launch_bounds__(256) void transpose_stage(
    const float* __restrict__ pred, const float* __restrict__ gt,
    unsigned short* __restrict__ Xs, unsigned short* __restrict__ Ys,
    int* __restrict__ cnt) {
  int blk = blockIdx.x;
  const int t = threadIdx.x;
  if (blk == 0 && t < 33) cnt[t] = 0;
  const float* src;
  unsigned short* dst;
  int slab;
  if (blk < 256) { src = pred; dst = Xs; slab = blk; }
  else           { src = gt;   dst = Ys; slab = blk - 256; }
  const float* sb = src + slab * 4096;
  const int rb = slab >> 3, rowhi = slab & 7;
  #pragma unroll
  for (int half = 0; half < 2; ++half) {
    int c_ = half * 256 + t;                 // chunk id within slab, 0..511
    int rowlo = c_ & 15;
    int quad  = (c_ >> 4) & 3;
    int kk    = (c_ >> 6) & 1;
    int s     = c_ >> 7;
    int k0 = s * 64 + kk * 32 + quad * 8;
    unsigned int packed[4];
    #pragma unroll
    for (int jj = 0; jj < 4; ++jj) {
      unsigned int lohi[2];
      #pragma unroll
      for (int e = 0; e < 2; ++e) {
        float f = sb[(k0 + jj * 2 + e) * 16 + rowlo];
        unsigned int u = __float_as_uint(f);
        lohi[e] = (u + 0x7FFFu + ((u >> 16) & 1u)) >> 16;   // RNE -> bf16
      }
      packed[jj] = lohi[0] | (lohi[1] << 16);
    }
    unsigned short* o = dst + rb * 32768 +
        (unsigned)(s * 1024 + kk * 512 + rowhi * 64 + quad * 16 + rowlo) * 8;
    uint4 v; v.x = packed[0]; v.y = packed[1]; v.z = packed[2]; v.w = packed[3];
    *reinterpret_cast<uint4*>(o) = v;
  }
}

// ---------------------------------------------------------------------------
// K1: per-wave 64x64 GEMM tile, no LDS, no barriers. 1024 blocks x 256 thr
// (4 waves); block tile = 64 rows x 256 cols (waves side-by-side in cols so
// A-fragment loads are identical across the block's waves -> L1 reuse).
// XCD-chunked mapping: per XCD 16 rowb x 8 colb -> A 512 KB + B 1 MB
// L2-resident. acc 4x4 frags (64 VGPR); launch_bounds(256,4) caps VGPR=128
// for 4 waves/SIMD (16 waves/CU).
// Fused epilogue: per-row (max,sum-exp) over this wave's 64 cols + diag.
// ---------------------------------------------------------------------------
__global__ __launch_bounds__(256, 4) void gemm_wave(
    const unsigned short* __restrict__ Xs, const unsigned short* __restrict__ Ys,
    float* __restrict__ pmax, float* __restrict__ psum, float* __restrict__ diag) {
  const int t = threadIdx.x;
  const int wv = t >> 6, lane = t & 63;
  const int b = blockIdx.x;
  const int xcd = b & 7, slot = b >> 3;            // slot 0..127
  const int rowb = ((xcd >> 1) << 4) | (slot & 15); // 0..63 (64-row tiles)
  const int colb = ((xcd & 1) << 3) | (slot >> 4);  // 0..15 (256-col groups)
  // Rows rowb*64..+63: rb = rowb>>1, rowhi = (rowb&1)*4 + fr (fr=0..3).
  // Cols colb*256 + wv*64..+63: cb = colb*2 + (wv>>1), colhi = (wv&1)*4 + fc.
  const int hh = rowb & 1, ch = wv & 1;
  const unsigned short* Ab = Xs + (rowb >> 1) * 32768 + (unsigned)lane * 8;
  const unsigned short* Bb = Ys + ((colb << 1) | (wv >> 1)) * 32768 +
                             (unsigned)lane * 8;

  floatx4 acc[4][4];
  const floatx4 zero = {0.f, 0.f, 0.f, 0.f};
  #pragma unroll
  for (int i = 0; i < 4; ++i)
    #pragma unroll
    for (int j = 0; j < 4; ++j) acc[i][j] = zero;

  #pragma unroll
  for (int ks = 0; ks < 8; ++ks) {                 // K-step of 32
    const unsigned off = (unsigned)(((ks >> 1) * 1024 + (ks & 1) * 512)) * 8;
    bf16x8 a[4], bf[4];
    #pragma unroll
    for (int fr = 0; fr < 4; ++fr)
      a[fr] = *reinterpret_cast<const bf16x8*>(
          Ab + off + (unsigned)((hh * 4 + fr) * 64) * 8);
    #pragma unroll
    for (int fc = 0; fc < 4; ++fc)
      bf[fc] = *reinterpret_cast<const bf16x8*>(
          Bb + off + (unsigned)((ch * 4 + fc) * 64) * 8);
    #pragma unroll
    for (int fr = 0; fr < 4; ++fr)
      #pragma unroll
      for (int fc = 0; fc < 4; ++fc)
        acc[fr][fc] = __builtin_amdgcn_mfma_f32_16x16x32_bf16(
            a[fr], bf[fc], acc[fr][fc], 0, 0, 0);
  }

  const int quad = lane >> 4, lc = lane & 15;

  // Diagonal: wave is on the diagonal iff colb*4 + wv == rowb. Then local
  // row fr*16+quad*4+r == local col fc*16+lc -> fc==fr, lc==quad*4+r.
  if (colb * 4 + wv == rowb) {
    #pragma unroll
    for (int fr = 0; fr < 4; ++fr)
      #pragma unroll
      for (int r = 0; r < 4; ++r)
        if (lc == quad * 4 + r)
          diag[rowb * 64 + fr * 16 + lc] = acc[fr][fr][r];
  }

  // Per-row partials over this wave's 64 cols. Row = fr*16+quad*4+r lives in
  // the 16 lanes of one quad (lc=0..15); shfl_xor 1,2,4,8 stays in-quad.
  #pragma unroll
  for (int fr = 0; fr < 4; ++fr) {
    #pragma unroll
    for (int r = 0; r < 4; ++r) {
      float v0 = acc[fr][0][r], v1 = acc[fr][1][r];
      float v2 = acc[fr][2][r], v3 = acc[fr][3][r];
      float m = fmaxf(fmaxf(v0, v1), fmaxf(v2, v3));
      #pragma unroll
      for (int sh = 1; sh < 16; sh <<= 1) m = fmaxf(m, __shfl_xor(m, sh, 64));
      float ss = __expf(v0 - m) + __expf(v1 - m) +
                 __expf(v2 - m) + __expf(v3 - m);
      #pragma unroll
      for (int sh = 1; sh < 16; sh <<= 1) ss += __shfl_xor(ss, sh, 64);
      if (lc == 0) {
        int grow = rowb * 64 + fr * 16 + quad * 4 + r;
        int p = grow * 64 + colb * 4 + wv;
        pmax[p] = m; psum[p] = ss;
      }
    }
  }
}

// ---------------------------------------------------------------------------
// K2: per-row combine of 64 col-group partials -> loss/correct, block-reduce;
// last of 16 blocks finalizes (16 fences total -- round-1 lesson: fence count
// must stay tiny).
// ---------------------------------------------------------------------------
__global__ __launch_bounds__(256) void combine_rows(
    const float* __restrict__ pmax, const float* __restrict__ psum,
    const float* __restrict__ diag,
    float* __restrict__ lpart, float* __restrict__ cpart,
    int* __restrict__ cnt, float* __restrict__ out) {
  int row = blockIdx.x * 256 + threadIdx.x;
  const float* pm = pmax + row * 64;
  const float* ps = psum + row * 64;
  float M = -3.4e38f;
  #pragma unroll 8
  for (int b = 0; b < 64; ++b) M = fmaxf(M, pm[b]);
  float S = 0.f;
  #pragma unroll 8
  for (int b = 0; b < 64; ++b) S += ps[b] * __expf(pm[b] - M);
  float d = diag[row];
  float lossr = logf(S) + M - d;
  float corr = (d == M) ? 1.f : 0.f;
  #pragma unroll
  for (int sh = 1; sh < 64; sh <<= 1) {
    lossr += __shfl_xor(lossr, sh, 64);
    corr  += __shfl_xor(corr,  sh, 64);
  }
  __shared__ float ls[4], cs[4];
  int wave = threadIdx.x >> 6, lane = threadIdx.x & 63;
  if (lane == 0) { ls[wave] = lossr; cs[wave] = corr; }
  __syncthreads();
  if (threadIdx.x == 0) {
    lpart[blockIdx.x] = ls[0] + ls[1] + ls[2] + ls[3];
    cpart[blockIdx.x] = cs[0] + cs[1] + cs[2] + cs[3];
    __threadfence();                     // release per-block partial
    if (atomicAdd(cnt, 1) == 15) {       // last arriver finalizes
      __threadfence();                   // acquire all partials
      float L = 0.f, C = 0.f;
      for (int i = 0; i < 16; ++i) { L += lpart[i]; C += cpart[i]; }
      out[0] = L * (1.f / 4096.f);
      out[1] = C * (100.f / 4096.f);
    }
  }
}

extern "C" void kernel_launch(void* const* d_in, const int* in_sizes, int n_in,
                              void* d_out, int out_size, void* d_ws, size_t ws_size,
                              hipStream_t stream) {
  const float* pred = (const float*)d_in[0];
  const float* gt   = (const float*)d_in[1];
  char* w = (char*)d_ws;
  unsigned short* Xbf = (unsigned short*)(w + OFF_X);
  unsigned short* Ybf = (unsigned short*)(w + OFF_Y);
  float* pmax  = (float*)(w + OFF_PMAX);
  float* psum  = (float*)(w + OFF_PSUM);
  float* diag  = (float*)(w + OFF_DIAG);
  float* lpart = (float*)(w + OFF_LPART);
  float* cpart = (float*)(w + OFF_CPART);
  int*   cnt   = (int*)(w + OFF_CNT);
  float* out   = (float*)d_out;

  transpose_stage<<<512, 256, 0, stream>>>(pred, gt, Xbf, Ybf, cnt);
  gemm_wave<<<1024, 256, 0, stream>>>(Xbf, Ybf, pmax, psum, diag);
  combine_rows<<<16, 256, 0, stream>>>(pmax, psum, diag, lpart, cpart, cnt, out);
}